// Round 13
// baseline (820.628 us; speedup 1.0000x reference)
//
#include <hip/hip_runtime.h>
#include <hip/hip_bf16.h>
#include <cstdint>

// ---------------------------------------------------------------------------
// LlamaMlpWithLora: T=2048, H=4096, I=11008, A=8, R=16, scale=0.5
// R13: single-sync dbuf GEMM + (1) stage-issues spread 2-per-quadrant
//      (m201 striping) + (2) setprio(1) around MFMA quadrants (T5; regime =
//      free-running waves within a K-step).
//   xa [T][4352] = [x | 0.5*v_g | 0.5*v_u];  B-hat [22016][4352] interleaved;
//   t^ [T][11136] = [silu(gate)*up | 0.5*v_d];  Wd^ [H][11136].
// ---------------------------------------------------------------------------

#define T_TOK 2048
#define H_DIM 4096
#define I_DIM 11008
#define R_LORA 16
#define KA1 4352    // H + 128(gate) + 128(up)
#define KA2 11136   // I + 128(down)
#define N_STK 22016 // 2*I (interleaved)

typedef __bf16 bf16x8 __attribute__((ext_vector_type(8)));
typedef float f32x4 __attribute__((ext_vector_type(4)));

__device__ __forceinline__ float bf2f(unsigned short u) {
    union { unsigned int i; float f; } v;
    v.i = ((unsigned int)u) << 16;
    return v.f;
}
__device__ __forceinline__ unsigned short f2bf(float f) {
    __bf16 b = (__bf16)f;
    unsigned short u;
    __builtin_memcpy(&u, &b, 2);
    return u;
}
__device__ __forceinline__ void cvt8(const float* s, unsigned short* d) {
    float4 a = reinterpret_cast<const float4*>(s)[0];
    float4 b = reinterpret_cast<const float4*>(s)[1];
    uint4 o;
    o.x = (unsigned)f2bf(a.x) | ((unsigned)f2bf(a.y) << 16);
    o.y = (unsigned)f2bf(a.z) | ((unsigned)f2bf(a.w) << 16);
    o.z = (unsigned)f2bf(b.x) | ((unsigned)f2bf(b.y) << 16);
    o.w = (unsigned)f2bf(b.z) | ((unsigned)f2bf(b.w) << 16);
    *reinterpret_cast<uint4*>(d) = o;
}
__device__ __forceinline__ void gload_lds16(const void* g, void* l) {
    __builtin_amdgcn_global_load_lds(
        (const __attribute__((address_space(1))) void*)g,
        (__attribute__((address_space(3))) void*)l,
        16, 0, 0);
}

// ---------------- small kernels --------------------------------------------
__global__ __launch_bounds__(256) void cvt_rows(
    const float* __restrict__ src, unsigned short* __restrict__ dst, int K)
{
    const int row = blockIdx.x;
    const int tid = threadIdx.x;
    const float* s = src + (size_t)row * K;
    unsigned short* d = dst + (size_t)row * K;
    for (int k = tid * 8; k < K; k += 256 * 8) cvt8(s + k, d + k);
}

__global__ __launch_bounds__(256) void build_xa_x(
    const float* __restrict__ x, unsigned short* __restrict__ xa)
{
    const int t = blockIdx.x;
    const int tid = threadIdx.x;
    const float* s = x + (size_t)t * H_DIM;
    unsigned short* d = xa + (size_t)t * KA1;
    for (int k = tid * 8; k < H_DIM; k += 2048) cvt8(s + k, d + k);
}

__global__ __launch_bounds__(256) void fill_xa_aug(
    const float* __restrict__ P, const int* __restrict__ idx,
    unsigned short* __restrict__ xa)
{
    const int t = blockIdx.x;
    const int tid = threadIdx.x;
    const int a = (tid & 127) >> 4;
    float v = 0.f;
    if (a == idx[t]) {
        #pragma unroll
        for (int s = 0; s < 4; ++s)
            v += P[((size_t)s * T_TOK + t) * 256 + tid];
        v *= 0.5f;
    }
    xa[(size_t)t * KA1 + H_DIM + tid] = f2bf(v);
}

__global__ __launch_bounds__(128) void fill_ta(
    const float* __restrict__ P, const int* __restrict__ idx,
    unsigned short* __restrict__ t_aug)
{
    const int t = blockIdx.x;
    const int tid = threadIdx.x;
    const int a = tid >> 4;
    float v = 0.f;
    if (a == idx[t]) {
        #pragma unroll
        for (int s = 0; s < 4; ++s)
            v += P[((size_t)s * T_TOK + t) * 128 + tid];
        v *= 0.5f;
    }
    t_aug[(size_t)t * KA2 + I_DIM + tid] = f2bf(v);
}

// Interleaved gate/up weight builder: B-hat row 2i = gate_i, 2i+1 = up_i.
__global__ __launch_bounds__(256) void build_w_int(
    const float* __restrict__ gw, const float* __restrict__ uw,
    const float* __restrict__ gwb, const float* __restrict__ uwb,
    unsigned short* __restrict__ dst)
{
    const int c = blockIdx.x;
    const int i = c >> 1;
    const int par = c & 1;              // 0=gate, 1=up
    const int tid = threadIdx.x;
    const float* src = (par ? uw : gw) + (size_t)i * H_DIM;
    const float* wb  = (par ? uwb : gwb);
    unsigned short* d = dst + (size_t)c * KA1;
    for (int k = tid * 8; k < H_DIM; k += 256 * 8) cvt8(src + k, d + k);
    if (tid < 128) {
        const int a = tid >> 4, r = tid & 15;
        const float v = wb[(((size_t)a * I_DIM) + i) * R_LORA + r];
        d[H_DIM + par * 128 + tid] = f2bf(v);
        d[H_DIM + (1 - par) * 128 + tid] = 0;
    }
}

__global__ __launch_bounds__(256) void build_w_aug(
    const float* __restrict__ w, const float* __restrict__ wb,
    unsigned short* __restrict__ dst,
    int Nrows, int Ksrc, int Kdst, int self_off)
{
    const int c = blockIdx.x;
    const int tid = threadIdx.x;
    const float* src = w + (size_t)c * Ksrc;
    unsigned short* d = dst + (size_t)c * Kdst;
    for (int k = tid * 8; k < Ksrc; k += 256 * 8) cvt8(src + k, d + k);
    if (tid < 128) {
        const int a = tid >> 4, r = tid & 15;
        const float v = wb[(((size_t)a * Nrows) + c) * R_LORA + r];
        d[self_off + tid] = f2bf(v);
    }
}

__global__ __launch_bounds__(256) void add_inplace(
    float* __restrict__ out, const float* __restrict__ p)
{
    const long long n4 = (long long)T_TOK * H_DIM / 4;
    long long i = (long long)blockIdx.x * 256 + threadIdx.x;
    const long long stride = (long long)gridDim.x * 256;
    for (; i < n4; i += stride) {
        float4 a = reinterpret_cast<float4*>(out)[i];
        float4 b = reinterpret_cast<const float4*>(p)[i];
        a.x += b.x; a.y += b.y; a.z += b.z; a.w += b.w;
        reinterpret_cast<float4*>(out)[i] = a;
    }
}

// ---------------- thin GEMM, split-K x4 -------------------------------------
__global__ __launch_bounds__(512) void gemm_thin_sk(
    const unsigned short* __restrict__ A, int lda,
    const unsigned short* __restrict__ B, int ldb,
    float* __restrict__ P, int N, int K)
{
    __shared__ __align__(16) unsigned short As[128][64];
    __shared__ __align__(16) unsigned short Bs[128][64];

    const int tid = threadIdx.x;
    const int lane = tid & 63;
    const int wid = tid >> 6;
    const int wr = wid >> 2;
    const int wc = wid & 3;
    const int fr = lane & 15;
    const int hi = lane >> 4;
    const int fsw = fr & 7;

    const int bm0 = blockIdx.y * 128;
    const int bn0 = blockIdx.x * 128;
    const int ks = K / 4;
    const int k0 = blockIdx.z * ks;
    float* out = P + (size_t)blockIdx.z * T_TOK * N;

    const int srow = tid >> 3;
    const int sslot = tid & 7;
    const int gcol = (sslot ^ (srow & 7)) * 8;
    const unsigned short* Ag = A + (size_t)(bm0 + srow) * lda + gcol;
    const unsigned short* Bg = B + (size_t)(bn0 + srow) * ldb + gcol;
    const size_t halfA = (size_t)64 * lda;
    const size_t halfB = (size_t)64 * ldb;

    f32x4 acc[4][2] = {};

    for (int kt = k0; kt < k0 + ks; kt += 64) {
        gload_lds16(Ag + kt,         &As[srow][sslot * 8]);
        gload_lds16(Ag + halfA + kt, &As[64 + srow][sslot * 8]);
        gload_lds16(Bg + kt,         &Bs[srow][sslot * 8]);
        gload_lds16(Bg + halfB + kt, &Bs[64 + srow][sslot * 8]);
        __syncthreads();
        #pragma unroll
        for (int kk = 0; kk < 2; ++kk) {
            bf16x8 a_[4], b_[2];
            #pragma unroll
            for (int m = 0; m < 4; ++m)
                a_[m] = *reinterpret_cast<const bf16x8*>(
                    &As[wr * 64 + m * 16 + fr][((kk * 4 + hi) ^ fsw) * 8]);
            #pragma unroll
            for (int n = 0; n < 2; ++n)
                b_[n] = *reinterpret_cast<const bf16x8*>(
                    &Bs[wc * 32 + n * 16 + fr][((kk * 4 + hi) ^ fsw) * 8]);
            #pragma unroll
            for (int m = 0; m < 4; ++m)
                #pragma unroll
                for (int n = 0; n < 2; ++n)
                    acc[m][n] = __builtin_amdgcn_mfma_f32_16x16x32_bf16(
                        a_[m], b_[n], acc[m][n], 0, 0, 0);
        }
        __syncthreads();
    }

    const int orow0 = bm0 + wr * 64 + hi * 4;
    const int ocol0 = bn0 + wc * 32 + fr;
    #pragma unroll
    for (int m = 0; m < 4; ++m)
        #pragma unroll
        for (int j = 0; j < 4; ++j) {
            const int row = orow0 + m * 16 + j;
            #pragma unroll
            for (int n = 0; n < 2; ++n)
                out[(size_t)row * N + ocol0 + n * 16] = acc[m][n][j];
        }
}

// ---------------- main GEMM: dbuf, striped stage, setprio, one sync --------
// BM=BN=256, BK=64. 8 waves 2Mx4N, per-wave 128x64, acc 8x4 f32x4.
// MODE 3: pass1 interleaved -> fused silu*mul epilogue, bf16 t out.
// MODE 2: pass2 down split-K x2 with 2D XCD map (4M x 2N x 2K groups).
#define RD_A(BUF, MH)                                                         \
    do {                                                                      \
        _Pragma("unroll")                                                     \
        for (int mq = 0; mq < 4; ++mq) {                                      \
            _Pragma("unroll")                                                 \
            for (int k = 0; k < 2; ++k)                                       \
                a_[mq][k] = *reinterpret_cast<const bf16x8*>(                 \
                    &lds[BUF][wr * 128 + (MH) * 64 + mq * 16 + fr]            \
                        [((k * 4 + hi) ^ fsw) * 8]);                          \
        }                                                                     \
    } while (0)

#define RD_B(BUF, NH, DST)                                                    \
    do {                                                                      \
        _Pragma("unroll")                                                     \
        for (int nq = 0; nq < 2; ++nq) {                                      \
            _Pragma("unroll")                                                 \
            for (int k = 0; k < 2; ++k)                                       \
                DST[nq][k] = *reinterpret_cast<const bf16x8*>(                \
                    &lds[BUF][256 + wc * 64 + (NH) * 32 + nq * 16 + fr]       \
                        [((k * 4 + hi) ^ fsw) * 8]);                          \
        }                                                                     \
    } while (0)

#define MM(MH, NH, BSRC)                                                      \
    do {                                                                      \
        __builtin_amdgcn_s_setprio(1);                                        \
        _Pragma("unroll")                                                     \
        for (int mq = 0; mq < 4; ++mq) {                                      \
            _Pragma("unroll")                                                 \
            for (int nq = 0; nq < 2; ++nq) {                                  \
                _Pragma("unroll")                                             \
                for (int k = 0; k < 2; ++k)                                   \
                    acc[(MH) * 4 + mq][(NH) * 2 + nq] =                       \
                        __builtin_amdgcn_mfma_f32_16x16x32_bf16(              \
                            a_[mq][k], BSRC[nq][k],                           \
                            acc[(MH) * 4 + mq][(NH) * 2 + nq], 0, 0, 0);      \
            }                                                                 \
        }                                                                     \
        __builtin_amdgcn_s_setprio(0);                                        \
    } while (0)

template <int MODE>
__global__ __launch_bounds__(512, 2) void gemmk(
    const unsigned short* __restrict__ A, int lda,
    const unsigned short* __restrict__ B, int ldb,
    int nks_in,
    unsigned short* __restrict__ outb,
    float* __restrict__ outf0, float* __restrict__ outf1)
{
    __shared__ __align__(16) unsigned short lds[2][512][64];

    const int tid = threadIdx.x;
    const int lane = tid & 63;
    const int wid = tid >> 6;
    const int wr = wid >> 2;      // 0..1 (M half, 128 rows)
    const int wc = wid & 3;       // 0..3 (N quarter, 64 cols)
    const int fr = lane & 15;
    const int hi = lane >> 4;
    const int fsw = fr & 7;

    int bm, bn, koff = 0, nks = nks_in;
    float* outf = outf0;
    if constexpr (MODE == 2) {
        const int xcd = blockIdx.x & 7;
        const int c = blockIdx.x >> 3;          // 0..31
        bm = (xcd >> 1) * 2 + (c & 1);
        bn = (xcd & 1) * 8 + ((c >> 1) & 7);
        nks = 87;                               // KA2/64 = 174 = 87+87
        if (c >> 4) { koff = 87 * 64; outf = outf1; }
    } else {
        bm = blockIdx.x & 7;      // XCD-pinned A-slab
        bn = blockIdx.x >> 3;
    }
    const int bm0 = bm * 256;
    const int bn0 = bn * 256;

    const int srow = tid >> 3;
    const int sslot = tid & 7;
    const int gcol = (sslot ^ (srow & 7)) * 8;
    const unsigned short* Ap = A + (size_t)(bm0 + srow) * lda + gcol + koff;
    const unsigned short* Bp = B + (size_t)(bn0 + srow) * ldb + gcol + koff;

    f32x4 acc[8][4] = {};
    bf16x8 a_[4][2], b0_[2][2], b1_[2][2];

    // staging striped into 4 pairs (m201-style smooth VMEM issue)
    auto stA2 = [&](int buf, int kt, int h) {     // h=0: q0,q1  h=1: q2,q3
        #pragma unroll
        for (int q = 0; q < 2; ++q)
            gload_lds16(Ap + (size_t)((h * 2 + q) * 64) * lda + kt,
                        &lds[buf][(h * 2 + q) * 64 + srow][sslot * 8]);
    };
    auto stB2 = [&](int buf, int kt, int h) {
        #pragma unroll
        for (int q = 0; q < 2; ++q)
            gload_lds16(Bp + (size_t)((h * 2 + q) * 64) * ldb + kt,
                        &lds[buf][256 + (h * 2 + q) * 64 + srow][sslot * 8]);
    };

    // prologue: K-step 0 into buf0
    stA2(0, 0, 0); stA2(0, 0, 1); stB2(0, 0, 0); stB2(0, 0, 1);
    __syncthreads();

    for (int t = 0; t < nks; ++t) {
        const int cur = t & 1;
        const int nxt = cur ^ 1;
        const bool pre = (t + 1 < nks);
        const int ktn = (t + 1) * 64;

        RD_A(cur, 0);
        RD_B(cur, 0, b0_);
        if (pre) stA2(nxt, ktn, 0);
        MM(0, 0, b0_);

        RD_B(cur, 1, b1_);
        if (pre) stA2(nxt, ktn, 1);
        MM(0, 1, b1_);

        RD_A(cur, 1);
        if (pre) stB2(nxt, ktn, 0);
        MM(1, 0, b0_);

        if (pre) stB2(nxt, ktn, 1);
        MM(1, 1, b1_);

        __syncthreads();   // vmcnt(0)+lgkmcnt(0)+barrier: K-step boundary
    }

    // Epilogue. C/D layout: col = lane&15, row = (lane>>4)*4 + reg.
    const int orow0 = bm0 + wr * 128 + hi * 4;
    const int ocol0 = bn0 + wc * 64 + fr;
    #pragma unroll
    for (int m = 0; m < 8; ++m) {
        #pragma unroll
        for (int jj = 0; jj < 4; ++jj) {
            const int row = orow0 + m * 16 + jj;
            #pragma unroll
            for (int n = 0; n < 4; ++n) {
                if constexpr (MODE == 3) {
                    // interleaved: even lane = gate, odd = up of same column
                    const float v = acc[m][n][jj];
                    const float w = __shfl_xor(v, 1);
                    if ((fr & 1) == 0) {
                        const float sg = v / (1.f + __expf(-v));
                        const int s = ocol0 + n * 16;
                        outb[(size_t)row * KA2 + (s >> 1)] = f2bf(sg * w);
                    }
                } else {
                    outf[(size_t)row * H_DIM + ocol0 + n * 16] = acc[m][n][jj];
                }
            }
        }
    }
}

// ---------------------------------------------------------------------------
extern "C" void kernel_launch(void* const* d_in, const int* in_sizes, int n_in,
                              void* d_out, int out_size, void* d_ws, size_t ws_size,
                              hipStream_t stream)
{
    const float* x       = (const float*)d_in[0];
    const float* gate_w  = (const float*)d_in[1];
    const float* up_w    = (const float*)d_in[2];
    const float* down_w  = (const float*)d_in[3];
    const float* gate_wa = (const float*)d_in[4];
    const float* gate_wb = (const float*)d_in[5];
    const float* up_wa   = (const float*)d_in[6];
    const float* up_wb   = (const float*)d_in[7];
    const float* down_wa = (const float*)d_in[8];
    const float* down_wb = (const float*)d_in[9];
    const int*   indices = (const int*)d_in[10];
    float* out = (float*)d_out;

    char* ws = (char*)d_ws;
    size_t off = 0;
    auto alloc = [&](size_t bytes) {
        char* p = ws + off;
        off += (bytes + 255) & ~(size_t)255;
        return p;
    };
    unsigned short* xa    = (unsigned short*)alloc((size_t)T_TOK * KA1 * 2);   // 17.8MB
    unsigned short* wB    = (unsigned short*)alloc((size_t)N_STK * KA1 * 2);   // 191.6MB
    unsigned short* t_aug = (unsigned short*)alloc((size_t)T_TOK * KA2 * 2);   // 45.6MB
    unsigned short* wab_gu = (unsigned short*)alloc((size_t)256 * H_DIM * 2);  // 2MB

    // overlays (dead-range reuse):
    float* Pgu = (float*)t_aug;                       // 8MB, dead pre-pass1
    float* Pd  = (float*)xa;                          // 4MB, xa dead post-pass1
    unsigned short* wd_aug = wB;                      // 91.3MB, wB dead post-pass1
    unsigned short* wab_d  = wB + (size_t)H_DIM * KA2;            // 2.8MB
    float* partial1 = (float*)(wab_d + (size_t)128 * I_DIM + 64); // 32MB

    // --- LoRA-A projections (split-K x4 thin GEMMs) ---
    cvt_rows<<<128, 256, 0, stream>>>(gate_wa, wab_gu, H_DIM);
    cvt_rows<<<128, 256, 0, stream>>>(up_wa, wab_gu + (size_t)128 * H_DIM, H_DIM);
    build_xa_x<<<T_TOK, 256, 0, stream>>>(x, xa);
    gemm_thin_sk<<<dim3(2, 16, 4), 512, 0, stream>>>(xa, KA1, wab_gu, H_DIM, Pgu, 256, H_DIM);
    fill_xa_aug<<<T_TOK, 256, 0, stream>>>(Pgu, indices, xa);

    // --- interleaved stacked weights ---
    build_w_int<<<N_STK, 256, 0, stream>>>(gate_w, up_w, gate_wb, up_wb, wB);

    // --- pass 1: fused gate+up+silu -> t_aug (grid 8 bm x 86 bn) ---
    gemmk<3><<<8 * (N_STK / 256), 512, 0, stream>>>(
        xa, KA1, wB, KA1, KA1 / 64, t_aug, nullptr, nullptr);

    // --- down LoRA (split-K x4) + weights ---
    cvt_rows<<<128, 256, 0, stream>>>(down_wa, wab_d, I_DIM);
    gemm_thin_sk<<<dim3(1, 16, 4), 512, 0, stream>>>(t_aug, KA2, wab_d, I_DIM, Pd, 128, I_DIM);
    fill_ta<<<T_TOK, 128, 0, stream>>>(Pd, indices, t_aug);
    build_w_aug<<<H_DIM, 256, 0, stream>>>(down_w, down_wb, wd_aug,
                                           H_DIM, I_DIM, KA2, I_DIM);

    // --- pass 2: down split-K x2 (grid 256, 2D XCD map) + add ---
    gemmk<2><<<256, 512, 0, stream>>>(
        t_aug, KA2, wd_aug, KA2, 0, nullptr, out, partial1);
    add_inplace<<<2048, 256, 0, stream>>>(out, partial1);

    (void)in_sizes; (void)n_in; (void)out_size; (void)ws_size;
}

// Round 15
// 805.631 us; speedup vs baseline: 1.0186x; 1.0186x over previous
//
#include <hip/hip_runtime.h>
#include <hip/hip_bf16.h>
#include <cstdint>

// ---------------------------------------------------------------------------
// LlamaMlpWithLora: T=2048, H=4096, I=11008, A=8, R=16, scale=0.5
// R15: R14 structure with the overlay-ordering bug fixed — wab_d and partial1
//      get dedicated allocations (no overlay into wB, which build_w_int
//      writes between wab_d's def and use in R14).
//   xa [T][4352] = [x | 0.5*v_g | 0.5*v_u];  B-hat [22016][4352] interleaved;
//   t^ [T][11136] = [silu(gate)*up | 0.5*v_d];  Wd^ [H][11136].
// ---------------------------------------------------------------------------

#define T_TOK 2048
#define H_DIM 4096
#define I_DIM 11008
#define R_LORA 16
#define KA1 4352    // H + 128(gate) + 128(up)
#define KA2 11136   // I + 128(down)
#define N_STK 22016 // 2*I (interleaved)

typedef __bf16 bf16x8 __attribute__((ext_vector_type(8)));
typedef float f32x4 __attribute__((ext_vector_type(4)));

__device__ __forceinline__ float bf2f(unsigned short u) {
    union { unsigned int i; float f; } v;
    v.i = ((unsigned int)u) << 16;
    return v.f;
}
__device__ __forceinline__ unsigned short f2bf(float f) {
    __bf16 b = (__bf16)f;
    unsigned short u;
    __builtin_memcpy(&u, &b, 2);
    return u;
}
__device__ __forceinline__ void cvt8(const float* s, unsigned short* d) {
    float4 a = reinterpret_cast<const float4*>(s)[0];
    float4 b = reinterpret_cast<const float4*>(s)[1];
    uint4 o;
    o.x = (unsigned)f2bf(a.x) | ((unsigned)f2bf(a.y) << 16);
    o.y = (unsigned)f2bf(a.z) | ((unsigned)f2bf(a.w) << 16);
    o.z = (unsigned)f2bf(b.x) | ((unsigned)f2bf(b.y) << 16);
    o.w = (unsigned)f2bf(b.z) | ((unsigned)f2bf(b.w) << 16);
    *reinterpret_cast<uint4*>(d) = o;
}
__device__ __forceinline__ void gload_lds16(const void* g, void* l) {
    __builtin_amdgcn_global_load_lds(
        (const __attribute__((address_space(1))) void*)g,
        (__attribute__((address_space(3))) void*)l,
        16, 0, 0);
}

// ---------------- small kernels --------------------------------------------
// merged: rows 0-127 gate_wa, 128-255 up_wa -> wab_gu; 256-383 down_wa -> wab_d
__global__ __launch_bounds__(256) void cvt_wa_all(
    const float* __restrict__ gwa, const float* __restrict__ uwa,
    const float* __restrict__ dwa,
    unsigned short* __restrict__ wab_gu, unsigned short* __restrict__ wab_d)
{
    const int row = blockIdx.x;
    const int tid = threadIdx.x;
    if (row < 256) {
        const float* s = (row < 128 ? gwa + (size_t)row * H_DIM
                                    : uwa + (size_t)(row - 128) * H_DIM);
        unsigned short* d = wab_gu + (size_t)row * H_DIM;
        for (int k = tid * 8; k < H_DIM; k += 2048) cvt8(s + k, d + k);
    } else {
        const int r = row - 256;
        const float* s = dwa + (size_t)r * I_DIM;
        unsigned short* d = wab_d + (size_t)r * I_DIM;
        for (int k = tid * 8; k < I_DIM; k += 2048) cvt8(s + k, d + k);
    }
}

__global__ __launch_bounds__(256) void build_xa_x(
    const float* __restrict__ x, unsigned short* __restrict__ xa)
{
    const int t = blockIdx.x;
    const int tid = threadIdx.x;
    const float* s = x + (size_t)t * H_DIM;
    unsigned short* d = xa + (size_t)t * KA1;
    for (int k = tid * 8; k < H_DIM; k += 2048) cvt8(s + k, d + k);
}

__global__ __launch_bounds__(256) void fill_xa_aug(
    const float* __restrict__ P, const int* __restrict__ idx,
    unsigned short* __restrict__ xa)
{
    const int t = blockIdx.x;
    const int tid = threadIdx.x;
    const int a = (tid & 127) >> 4;
    float v = 0.f;
    if (a == idx[t]) {
        #pragma unroll
        for (int s = 0; s < 4; ++s)
            v += P[((size_t)s * T_TOK + t) * 256 + tid];
        v *= 0.5f;
    }
    xa[(size_t)t * KA1 + H_DIM + tid] = f2bf(v);
}

__global__ __launch_bounds__(128) void fill_ta(
    const float* __restrict__ P, const int* __restrict__ idx,
    unsigned short* __restrict__ t_aug)
{
    const int t = blockIdx.x;
    const int tid = threadIdx.x;
    const int a = tid >> 4;
    float v = 0.f;
    if (a == idx[t]) {
        #pragma unroll
        for (int s = 0; s < 4; ++s)
            v += P[((size_t)s * T_TOK + t) * 128 + tid];
        v *= 0.5f;
    }
    t_aug[(size_t)t * KA2 + I_DIM + tid] = f2bf(v);
}

// Interleaved gate/up weight builder: B-hat row 2i = gate_i, 2i+1 = up_i.
__global__ __launch_bounds__(256) void build_w_int(
    const float* __restrict__ gw, const float* __restrict__ uw,
    const float* __restrict__ gwb, const float* __restrict__ uwb,
    unsigned short* __restrict__ dst)
{
    const int c = blockIdx.x;
    const int i = c >> 1;
    const int par = c & 1;              // 0=gate, 1=up
    const int tid = threadIdx.x;
    const float* src = (par ? uw : gw) + (size_t)i * H_DIM;
    const float* wb  = (par ? uwb : gwb);
    unsigned short* d = dst + (size_t)c * KA1;
    for (int k = tid * 8; k < H_DIM; k += 256 * 8) cvt8(src + k, d + k);
    if (tid < 128) {
        const int a = tid >> 4, r = tid & 15;
        const float v = wb[(((size_t)a * I_DIM) + i) * R_LORA + r];
        d[H_DIM + par * 128 + tid] = f2bf(v);
        d[H_DIM + (1 - par) * 128 + tid] = 0;
    }
}

__global__ __launch_bounds__(256) void build_w_aug(
    const float* __restrict__ w, const float* __restrict__ wb,
    unsigned short* __restrict__ dst,
    int Nrows, int Ksrc, int Kdst, int self_off)
{
    const int c = blockIdx.x;
    const int tid = threadIdx.x;
    const float* src = w + (size_t)c * Ksrc;
    unsigned short* d = dst + (size_t)c * Kdst;
    for (int k = tid * 8; k < Ksrc; k += 256 * 8) cvt8(src + k, d + k);
    if (tid < 128) {
        const int a = tid >> 4, r = tid & 15;
        const float v = wb[(((size_t)a * Nrows) + c) * R_LORA + r];
        d[self_off + tid] = f2bf(v);
    }
}

__global__ __launch_bounds__(256) void add_inplace(
    float* __restrict__ out, const float* __restrict__ p)
{
    const long long n4 = (long long)T_TOK * H_DIM / 4;
    long long i = (long long)blockIdx.x * 256 + threadIdx.x;
    const long long stride = (long long)gridDim.x * 256;
    for (; i < n4; i += stride) {
        float4 a = reinterpret_cast<float4*>(out)[i];
        float4 b = reinterpret_cast<const float4*>(p)[i];
        a.x += b.x; a.y += b.y; a.z += b.z; a.w += b.w;
        reinterpret_cast<float4*>(out)[i] = a;
    }
}

// ---------------- thin GEMM, split-K x4 -------------------------------------
__global__ __launch_bounds__(512) void gemm_thin_sk(
    const unsigned short* __restrict__ A, int lda,
    const unsigned short* __restrict__ B, int ldb,
    float* __restrict__ P, int N, int K)
{
    __shared__ __align__(16) unsigned short As[128][64];
    __shared__ __align__(16) unsigned short Bs[128][64];

    const int tid = threadIdx.x;
    const int lane = tid & 63;
    const int wid = tid >> 6;
    const int wr = wid >> 2;
    const int wc = wid & 3;
    const int fr = lane & 15;
    const int hi = lane >> 4;
    const int fsw = fr & 7;

    const int bm0 = blockIdx.y * 128;
    const int bn0 = blockIdx.x * 128;
    const int ks = K / 4;
    const int k0 = blockIdx.z * ks;
    float* out = P + (size_t)blockIdx.z * T_TOK * N;

    const int srow = tid >> 3;
    const int sslot = tid & 7;
    const int gcol = (sslot ^ (srow & 7)) * 8;
    const unsigned short* Ag = A + (size_t)(bm0 + srow) * lda + gcol;
    const unsigned short* Bg = B + (size_t)(bn0 + srow) * ldb + gcol;
    const size_t halfA = (size_t)64 * lda;
    const size_t halfB = (size_t)64 * ldb;

    f32x4 acc[4][2] = {};

    for (int kt = k0; kt < k0 + ks; kt += 64) {
        gload_lds16(Ag + kt,         &As[srow][sslot * 8]);
        gload_lds16(Ag + halfA + kt, &As[64 + srow][sslot * 8]);
        gload_lds16(Bg + kt,         &Bs[srow][sslot * 8]);
        gload_lds16(Bg + halfB + kt, &Bs[64 + srow][sslot * 8]);
        __syncthreads();
        #pragma unroll
        for (int kk = 0; kk < 2; ++kk) {
            bf16x8 a_[4], b_[2];
            #pragma unroll
            for (int m = 0; m < 4; ++m)
                a_[m] = *reinterpret_cast<const bf16x8*>(
                    &As[wr * 64 + m * 16 + fr][((kk * 4 + hi) ^ fsw) * 8]);
            #pragma unroll
            for (int n = 0; n < 2; ++n)
                b_[n] = *reinterpret_cast<const bf16x8*>(
                    &Bs[wc * 32 + n * 16 + fr][((kk * 4 + hi) ^ fsw) * 8]);
            #pragma unroll
            for (int m = 0; m < 4; ++m)
                #pragma unroll
                for (int n = 0; n < 2; ++n)
                    acc[m][n] = __builtin_amdgcn_mfma_f32_16x16x32_bf16(
                        a_[m], b_[n], acc[m][n], 0, 0, 0);
        }
        __syncthreads();
    }

    const int orow0 = bm0 + wr * 64 + hi * 4;
    const int ocol0 = bn0 + wc * 32 + fr;
    #pragma unroll
    for (int m = 0; m < 4; ++m)
        #pragma unroll
        for (int j = 0; j < 4; ++j) {
            const int row = orow0 + m * 16 + j;
            #pragma unroll
            for (int n = 0; n < 2; ++n)
                out[(size_t)row * N + ocol0 + n * 16] = acc[m][n][j];
        }
}

// ---------------- main GEMM: dbuf, burst stage, one sync per K-step --------
// BM=BN=256, BK=64. 8 waves 2Mx4N, per-wave 128x64, acc 8x4 f32x4.
// MODE 3: pass1 interleaved -> fused silu*mul epilogue, bf16 t out.
// MODE 2: pass2 down split-K x2 with 2D XCD map (4M x 2N x 2K groups).
#define RD_A(BUF, MH)                                                         \
    do {                                                                      \
        _Pragma("unroll")                                                     \
        for (int mq = 0; mq < 4; ++mq) {                                      \
            _Pragma("unroll")                                                 \
            for (int k = 0; k < 2; ++k)                                       \
                a_[mq][k] = *reinterpret_cast<const bf16x8*>(                 \
                    &lds[BUF][wr * 128 + (MH) * 64 + mq * 16 + fr]            \
                        [((k * 4 + hi) ^ fsw) * 8]);                          \
        }                                                                     \
    } while (0)

#define RD_B(BUF, NH, DST)                                                    \
    do {                                                                      \
        _Pragma("unroll")                                                     \
        for (int nq = 0; nq < 2; ++nq) {                                      \
            _Pragma("unroll")                                                 \
            for (int k = 0; k < 2; ++k)                                       \
                DST[nq][k] = *reinterpret_cast<const bf16x8*>(                \
                    &lds[BUF][256 + wc * 64 + (NH) * 32 + nq * 16 + fr]       \
                        [((k * 4 + hi) ^ fsw) * 8]);                          \
        }                                                                     \
    } while (0)

#define MM(MH, NH, BSRC)                                                      \
    do {                                                                      \
        _Pragma("unroll")                                                     \
        for (int mq = 0; mq < 4; ++mq) {                                      \
            _Pragma("unroll")                                                 \
            for (int nq = 0; nq < 2; ++nq) {                                  \
                _Pragma("unroll")                                             \
                for (int k = 0; k < 2; ++k)                                   \
                    acc[(MH) * 4 + mq][(NH) * 2 + nq] =                       \
                        __builtin_amdgcn_mfma_f32_16x16x32_bf16(              \
                            a_[mq][k], BSRC[nq][k],                           \
                            acc[(MH) * 4 + mq][(NH) * 2 + nq], 0, 0, 0);      \
            }                                                                 \
        }                                                                     \
    } while (0)

template <int MODE>
__global__ __launch_bounds__(512, 2) void gemmk(
    const unsigned short* __restrict__ A, int lda,
    const unsigned short* __restrict__ B, int ldb,
    int nks_in,
    unsigned short* __restrict__ outb,
    float* __restrict__ outf0, float* __restrict__ outf1)
{
    __shared__ __align__(16) unsigned short lds[2][512][64];

    const int tid = threadIdx.x;
    const int lane = tid & 63;
    const int wid = tid >> 6;
    const int wr = wid >> 2;      // 0..1 (M half, 128 rows)
    const int wc = wid & 3;       // 0..3 (N quarter, 64 cols)
    const int fr = lane & 15;
    const int hi = lane >> 4;
    const int fsw = fr & 7;

    int bm, bn, koff = 0, nks = nks_in;
    float* outf = outf0;
    if constexpr (MODE == 2) {
        const int xcd = blockIdx.x & 7;
        const int c = blockIdx.x >> 3;          // 0..31
        bm = (xcd >> 1) * 2 + (c & 1);
        bn = (xcd & 1) * 8 + ((c >> 1) & 7);
        nks = 87;                               // KA2/64 = 174 = 87+87
        if (c >> 4) { koff = 87 * 64; outf = outf1; }
    } else {
        bm = blockIdx.x & 7;      // XCD-pinned A-slab
        bn = blockIdx.x >> 3;
    }
    const int bm0 = bm * 256;
    const int bn0 = bn * 256;

    const int srow = tid >> 3;
    const int sslot = tid & 7;
    const int gcol = (sslot ^ (srow & 7)) * 8;
    const unsigned short* Ap = A + (size_t)(bm0 + srow) * lda + gcol + koff;
    const unsigned short* Bp = B + (size_t)(bn0 + srow) * ldb + gcol + koff;

    f32x4 acc[8][4] = {};
    bf16x8 a_[4][2], b0_[2][2], b1_[2][2];

    auto stage = [&](int buf, int kt) {
        #pragma unroll
        for (int q = 0; q < 4; ++q)
            gload_lds16(Ap + (size_t)(q * 64) * lda + kt,
                        &lds[buf][q * 64 + srow][sslot * 8]);
        #pragma unroll
        for (int q = 0; q < 4; ++q)
            gload_lds16(Bp + (size_t)(q * 64) * ldb + kt,
                        &lds[buf][256 + q * 64 + srow][sslot * 8]);
    };

    // prologue: K-step 0 into buf0
    stage(0, 0);
    __syncthreads();

    for (int t = 0; t < nks; ++t) {
        const int cur = t & 1;
        if (t + 1 < nks) stage(cur ^ 1, (t + 1) * 64);   // burst issue, full slack

        RD_A(cur, 0);
        RD_B(cur, 0, b0_);
        MM(0, 0, b0_);
        RD_B(cur, 1, b1_);
        MM(0, 1, b1_);
        RD_A(cur, 1);
        MM(1, 0, b0_);
        MM(1, 1, b1_);

        __syncthreads();   // vmcnt(0)+lgkmcnt(0)+barrier: K-step boundary
    }

    // Epilogue. C/D layout: col = lane&15, row = (lane>>4)*4 + reg.
    const int orow0 = bm0 + wr * 128 + hi * 4;
    const int ocol0 = bn0 + wc * 64 + fr;
    #pragma unroll
    for (int m = 0; m < 8; ++m) {
        #pragma unroll
        for (int jj = 0; jj < 4; ++jj) {
            const int row = orow0 + m * 16 + jj;
            #pragma unroll
            for (int n = 0; n < 4; ++n) {
                if constexpr (MODE == 3) {
                    // interleaved: even lane = gate, odd = up of same column
                    const float v = acc[m][n][jj];
                    const float w = __shfl_xor(v, 1);
                    if ((fr & 1) == 0) {
                        const float sg = v / (1.f + __expf(-v));
                        const int s = ocol0 + n * 16;
                        outb[(size_t)row * KA2 + (s >> 1)] = f2bf(sg * w);
                    }
                } else {
                    outf[(size_t)row * H_DIM + ocol0 + n * 16] = acc[m][n][jj];
                }
            }
        }
    }
}

// ---------------------------------------------------------------------------
extern "C" void kernel_launch(void* const* d_in, const int* in_sizes, int n_in,
                              void* d_out, int out_size, void* d_ws, size_t ws_size,
                              hipStream_t stream)
{
    const float* x       = (const float*)d_in[0];
    const float* gate_w  = (const float*)d_in[1];
    const float* up_w    = (const float*)d_in[2];
    const float* down_w  = (const float*)d_in[3];
    const float* gate_wa = (const float*)d_in[4];
    const float* gate_wb = (const float*)d_in[5];
    const float* up_wa   = (const float*)d_in[6];
    const float* up_wb   = (const float*)d_in[7];
    const float* down_wa = (const float*)d_in[8];
    const float* down_wb = (const float*)d_in[9];
    const int*   indices = (const int*)d_in[10];
    float* out = (float*)d_out;

    char* ws = (char*)d_ws;
    size_t off = 0;
    auto alloc = [&](size_t bytes) {
        char* p = ws + off;
        off += (bytes + 255) & ~(size_t)255;
        return p;
    };
    unsigned short* xa     = (unsigned short*)alloc((size_t)T_TOK * KA1 * 2);   // 17.8MB
    unsigned short* wB     = (unsigned short*)alloc((size_t)N_STK * KA1 * 2);   // 191.6MB
    unsigned short* t_aug  = (unsigned short*)alloc((size_t)T_TOK * KA2 * 2);   // 45.6MB
    unsigned short* wab_gu = (unsigned short*)alloc((size_t)256 * H_DIM * 2);   // 2MB
    unsigned short* wab_d  = (unsigned short*)alloc((size_t)128 * I_DIM * 2);   // 2.8MB (own slot!)
    float* partial1        = (float*)alloc((size_t)T_TOK * H_DIM * 4);          // 32MB (own slot!)
    // total ~292MB (R10 proved >=347MB available)

    // safe overlays (no writer between def and use):
    float* Pgu = (float*)t_aug;        // def: gemm_thin_sk; use: fill_xa_aug; t_aug next written by pass1 (after)
    float* Pd  = (float*)xa;           // def: gemm_thin_sk (post-pass1); xa dead after pass1
    unsigned short* wd_aug = wB;       // def: build_w_aug (post-pass1); wB dead after pass1

    // --- LoRA-A weights bf16 (one merged launch) + xa build ---
    cvt_wa_all<<<384, 256, 0, stream>>>(gate_wa, up_wa, down_wa, wab_gu, wab_d);
    build_xa_x<<<T_TOK, 256, 0, stream>>>(x, xa);
    gemm_thin_sk<<<dim3(2, 16, 4), 512, 0, stream>>>(xa, KA1, wab_gu, H_DIM, Pgu, 256, H_DIM);
    fill_xa_aug<<<T_TOK, 256, 0, stream>>>(Pgu, indices, xa);

    // --- interleaved stacked weights ---
    build_w_int<<<N_STK, 256, 0, stream>>>(gate_w, up_w, gate_wb, up_wb, wB);

    // --- pass 1: fused gate+up+silu -> t_aug (grid 8 bm x 86 bn) ---
    gemmk<3><<<8 * (N_STK / 256), 512, 0, stream>>>(
        xa, KA1, wB, KA1, KA1 / 64, t_aug, nullptr, nullptr);

    // --- down LoRA (split-K x4; wab_d in its own slot, built up-front) ---
    gemm_thin_sk<<<dim3(1, 16, 4), 512, 0, stream>>>(t_aug, KA2, wab_d, I_DIM, Pd, 128, I_DIM);
    fill_ta<<<T_TOK, 128, 0, stream>>>(Pd, indices, t_aug);
    build_w_aug<<<H_DIM, 256, 0, stream>>>(down_w, down_wb, wd_aug,
                                           H_DIM, I_DIM, KA2, I_DIM);

    // --- pass 2: down split-K x2 (grid 256, 2D XCD map) + add ---
    gemmk<2><<<256, 512, 0, stream>>>(
        t_aug, KA2, wd_aug, KA2, 0, nullptr, out, partial1);
    add_inplace<<<2048, 256, 0, stream>>>(out, partial1);

    (void)in_sizes; (void)n_in; (void)out_size; (void)ws_size;
}